// Round 5
// baseline (538.558 us; speedup 1.0000x reference)
//
#include <hip/hip_runtime.h>
#include <cmath>

typedef _Float16 f16;
typedef _Float16 f16x8 __attribute__((ext_vector_type(8)));
typedef float f32x4 __attribute__((ext_vector_type(4)));
typedef unsigned long long u64;

#define M_OUT 2049          // N//2 + 1
#define NDIM 4096
#define MPAD 2112           // 2049 padded to 64-multiple (33 tiles)
// reference: -2.0 * 3.14 / N computed in f64, rounded once to f32
#define CW ((float)(-2.0 * 3.14 / 4096.0))

// ws layout:
//   [0, 16384)             row means (4096 f32)
//   [16384, 16384+2049*8)  argmax cells (u64, packed (amp2_bits<<32)|~col)
//   [40960, ...)           tables (layout depends on path)
// FULL path (chunk-major):
//   A tables: Ach,Acl,Ash,Asl each [512][2112][8] f16   (4 x 17.3 MB)
//   X tables: Xh,Xl           each [512][4096][8] f16   (2 x 33.6 MB)
// MID path (row-major): Ach,Acl,Ash,Asl each [2112][4096] f16
static const size_t WS_MEAN  = 0;
static const size_t WS_CELLS = 16384;
static const size_t WS_TBL   = 40960;
static const size_t A_ELEMS  = (size_t)MPAD * NDIM;        // 8650752
static const size_t X_ELEMS  = (size_t)NDIM * NDIM;        // 16777216
static const size_t WS_XTBL  = WS_TBL + 4 * A_ELEMS * sizeof(f16);
static const size_t WS_FULL_END = WS_XTBL + 2 * X_ELEMS * sizeof(f16);
static const size_t WS_MID_END  = WS_TBL + 4 * A_ELEMS * sizeof(f16);

#define AS1 __attribute__((address_space(1)))
#define AS3 __attribute__((address_space(3)))
__device__ __forceinline__ void async_copy16(const void* gsrc, void* ldst) {
    __builtin_amdgcn_global_load_lds((const AS1 unsigned int*)gsrc,
                                     (AS3 unsigned int*)ldst, 16, 0, 0);
}

__device__ __forceinline__ void split_f16(float v, f16& hi, f16& lo) {
    hi = (f16)v;
    lo = (f16)((v - (float)hi) * 64.0f);
}

// ---------------- row means (+ argmax-cell init in first 9 blocks) ----------------
__global__ void mean_kernel(const float* __restrict__ x, float* __restrict__ meanv,
                            u64* __restrict__ cells) {
    if (blockIdx.x < 9) {
        int i = blockIdx.x * 256 + threadIdx.x;
        if (i < M_OUT) cells[i] = 0ull;
    }
    const int row = blockIdx.x;
    const float4* xr = (const float4*)(x + (size_t)row * NDIM);
    float s = 0.f;
    for (int i = threadIdx.x; i < NDIM / 4; i += 256) {
        float4 v = xr[i];
        s += (v.x + v.y) + (v.z + v.w);
    }
    for (int off = 32; off; off >>= 1) s += __shfl_down(s, off);
    __shared__ float ps[4];
    if ((threadIdx.x & 63) == 0) ps[threadIdx.x >> 6] = s;
    __syncthreads();
    if (threadIdx.x == 0) {
        float t = (ps[0] + ps[1]) + (ps[2] + ps[3]);
        meanv[row] = t * (1.0f / 4096.0f);
    }
}

// ================= FULL path: chunk-major tables (A + X merged, one launch) ========
// grid (512, 25): y in [0,9) -> A-table rows tile, y in [9,25) -> X-table col tile.
__global__ void fill_tables_cm(const float* __restrict__ x, const float* __restrict__ meanv,
                               f16* __restrict__ atbl, f16* __restrict__ xtbl) {
    const int c = blockIdx.x;                      // k-chunk 0..511
    if (blockIdx.y < 9) {
        const int m = blockIdx.y * 256 + threadIdx.x;  // 0..2303
        if (m >= MPAD) return;
        const bool valid = (m < M_OUT);
        f16x8 chv, clv, shv, slv;
        for (int j = 0; j < 8; ++j) {
            float cc = 0.f, ss = 0.f;
            if (valid) {
                int kk = c * 8 + j;
                float ang = CW * (float)(m * kk);      // m*kk < 2^24 -> exact
                sincosf(ang, &ss, &cc);
            }
            f16 h, l;
            split_f16(cc, h, l); chv[j] = h; clv[j] = l;
            split_f16(ss, h, l); shv[j] = h; slv[j] = l;
        }
        size_t idx = ((size_t)c * MPAD + m) * 8;
        *(f16x8*)(atbl + idx)                 = chv;
        *(f16x8*)(atbl + A_ELEMS + idx)       = clv;
        *(f16x8*)(atbl + 2 * A_ELEMS + idx)   = shv;
        *(f16x8*)(atbl + 3 * A_ELEMS + idx)   = slv;
    } else {
        const int n = (blockIdx.y - 9) * 256 + threadIdx.x;  // 0..4095
        f16x8 hv, lv;
        for (int j = 0; j < 8; ++j) {
            int k = c * 8 + j;
            float v = x[(size_t)k * NDIM + n] - meanv[k];
            f16 h, l;
            split_f16(v, h, l);
            hv[j] = h; lv[j] = l;
        }
        size_t idx = ((size_t)c * NDIM + n) * 8;
        *(f16x8*)(xtbl + idx)           = hv;
        *(f16x8*)(xtbl + X_ELEMS + idx) = lv;
    }
}

// Fused split-f16 DFT GEMM + argmax.
// A fragments: direct global->VGPR (contiguous 16B, chunk-major), double-buffered regs.
// X: TRIPLE-buffered LDS via global_load_lds.
// Pipeline: per K=32 phase, issue next phase's 8 A-loads + 4 X-DMAs at the TOP,
// raw s_barrier with COUNTED s_waitcnt vmcnt(12) (prev phase's batch drained;
// this phase's 12 stay in flight across the barrier). sched_barrier(0) after each
// s_barrier pins the ds_reads after the rendezvous. 3 X buffers make the restage
// WAR-safe. s_setprio(1) around the 48-MFMA cluster.
// Grid: 32 x 32 = 1024 blocks = EXACTLY 2 occupancy rounds at 2 blocks/CU.
// Nyquist row-tile (rows 2048..2111): blocks with blockIdx.y==0 (linear ids 0..31,
// dispatched first) run the whole K-pipeline a SECOND time for rowBase=2048 --
// they are 2*T_tile stragglers that start first, so the critical path stays ~2*T.
// Tile: BM=64 x BN=128 x BK=32. 256 threads = 4 waves (2x2 of 32x64).
__global__ __launch_bounds__(256, 2) void dft_gemm_cm(
    const f16* __restrict__ atbl, const f16* __restrict__ xtbl,
    u64* __restrict__ cells)
{
    __shared__ alignas(16) f16 sX[3][2][4][128][8];   // [buf][tbl][plane][n][8] = 48 KB

    const int t = threadIdx.x;
    const int n0 = blockIdx.x * 128;
    const int by = blockIdx.y;

    const int lane = t & 63;
    const int w  = t >> 6;
    const int wm = w >> 1, wn = w & 1;
    const int q  = lane >> 4, ln = lane & 15;

    f32x4 aC0[2][4], aC1[2][4], aS0[2][4], aS1[2][4];

    // X staging: 4 async ops per wave cover [2 tables][4 planes][2 halves]
    const int xq0 = w >> 1, xh = w & 1;
    const int xq1 = xq0 + 2;
    const f16* xG0 = xtbl + ((size_t)xq0 * NDIM + n0 + xh * 64 + lane) * 8;
    const f16* xG1 = xtbl + ((size_t)xq1 * NDIM + n0 + xh * 64 + lane) * 8;
    const f16* xG2 = xG0 + X_ELEMS;
    const f16* xG3 = xG1 + X_ELEMS;

    auto stageX = [&](int buf, int kc) {
        const size_t kadv = (size_t)kc * NDIM * 8;
        async_copy16(xG0 + kadv, &sX[buf][0][xq0][xh * 64][0]);
        async_copy16(xG1 + kadv, &sX[buf][0][xq1][xh * 64][0]);
        async_copy16(xG2 + kadv, &sX[buf][1][xq0][xh * 64][0]);
        async_copy16(xG3 + kadv, &sX[buf][1][xq1][xh * 64][0]);
    };

    auto compute = [&](f16x8 (&A)[2][4], int buf) {
        f16x8 bh[4], bl[4];
#pragma unroll
        for (int tn = 0; tn < 4; ++tn) {
            int nl = wn * 64 + tn * 16 + ln;
            bh[tn] = *(const f16x8*)&sX[buf][0][q][nl][0];
            bl[tn] = *(const f16x8*)&sX[buf][1][q][nl][0];
        }
        __builtin_amdgcn_s_setprio(1);
#pragma unroll
        for (int tm = 0; tm < 2; ++tm)
#pragma unroll
            for (int tn = 0; tn < 4; ++tn) {
                aC0[tm][tn] = __builtin_amdgcn_mfma_f32_16x16x32_f16(A[tm][0], bh[tn], aC0[tm][tn], 0, 0, 0);
                aC1[tm][tn] = __builtin_amdgcn_mfma_f32_16x16x32_f16(A[tm][0], bl[tn], aC1[tm][tn], 0, 0, 0);
                aC1[tm][tn] = __builtin_amdgcn_mfma_f32_16x16x32_f16(A[tm][1], bh[tn], aC1[tm][tn], 0, 0, 0);
                aS0[tm][tn] = __builtin_amdgcn_mfma_f32_16x16x32_f16(A[tm][2], bh[tn], aS0[tm][tn], 0, 0, 0);
                aS1[tm][tn] = __builtin_amdgcn_mfma_f32_16x16x32_f16(A[tm][2], bl[tn], aS1[tm][tn], 0, 0, 0);
                aS1[tm][tn] = __builtin_amdgcn_mfma_f32_16x16x32_f16(A[tm][3], bh[tn], aS1[tm][tn], 0, 0, 0);
            }
        __builtin_amdgcn_s_setprio(0);
    };

    f16x8 Aa[2][4], Ab[2][4];

    const int npass = (by == 0) ? 2 : 1;
    for (int pass = 0; pass < npass; ++pass) {
        const int rowBase = (pass == 0) ? by * 64 : 2048;
        // pass isolation: all waves' previous-pass LDS reads complete before restage
        __syncthreads();

#pragma unroll
        for (int i = 0; i < 2; ++i)
#pragma unroll
            for (int j = 0; j < 4; ++j) {
                aC0[i][j] = (f32x4){0.f, 0.f, 0.f, 0.f};
                aC1[i][j] = (f32x4){0.f, 0.f, 0.f, 0.f};
                aS0[i][j] = (f32x4){0.f, 0.f, 0.f, 0.f};
                aS1[i][j] = (f32x4){0.f, 0.f, 0.f, 0.f};
            }

        // A-fragment global base: row = rowBase + wm*32 + tm*16 + ln, chunk = kc + q
        const f16* aBase = atbl + ((size_t)q * MPAD + (rowBase + wm * 32 + ln)) * 8;

        auto loadA = [&](f16x8 (&dst)[2][4], int kc) {
#pragma unroll
            for (int tm = 0; tm < 2; ++tm)
#pragma unroll
                for (int tb = 0; tb < 4; ++tb)
                    dst[tm][tb] = *(const f16x8*)(aBase + (size_t)tb * A_ELEMS
                                  + ((size_t)kc * MPAD + tm * 16) * 8);
        };

        int cur = 0, nxt = 1;
        auto bump = [&]() { cur = nxt; nxt = (nxt == 2) ? 0 : nxt + 1; };

        // prologue: phase 0's batch in flight
        stageX(0, 0);
        loadA(Aa, 0);

        int kc = 0;   // chunk index (8 f16 per chunk); K=32 per phase -> step 4; 128 phases
        for (int it = 0; it < 63; ++it) {
            // even phase: compute Aa/buf cur, issue batch for next phase
            loadA(Ab, kc + 4);
            stageX(nxt, kc + 4);
            asm volatile("s_waitcnt vmcnt(12)" ::: "memory");   // prev batch landed; 12 new fly on
            __builtin_amdgcn_s_barrier();
            __builtin_amdgcn_sched_barrier(0);
            compute(Aa, cur);
            bump();
            kc += 4;
            // odd phase
            loadA(Aa, kc + 4);
            stageX(nxt, kc + 4);
            asm volatile("s_waitcnt vmcnt(12)" ::: "memory");
            __builtin_amdgcn_s_barrier();
            __builtin_amdgcn_sched_barrier(0);
            compute(Ab, cur);
            bump();
            kc += 4;
        }
        // phase 126: issue final batch (chunks 508..511)
        loadA(Ab, kc + 4);
        stageX(nxt, kc + 4);
        asm volatile("s_waitcnt vmcnt(12)" ::: "memory");
        __builtin_amdgcn_s_barrier();
        __builtin_amdgcn_sched_barrier(0);
        compute(Aa, cur);
        bump();
        // phase 127: last — full drain
        asm volatile("s_waitcnt vmcnt(0)" ::: "memory");
        __builtin_amdgcn_s_barrier();
        __builtin_amdgcn_sched_barrier(0);
        compute(Ab, cur);

        // ---- epilogue: amp^2, per-row argmax, atomicMax into cells ----
        const float inv64 = 0.015625f;
#pragma unroll
        for (int tm = 0; tm < 2; ++tm) {
#pragma unroll
            for (int r = 0; r < 4; ++r) {
                u64 best = 0ull;
#pragma unroll
                for (int tn = 0; tn < 4; ++tn) {
                    float C = aC0[tm][tn][r] + aC1[tm][tn][r] * inv64;
                    float S = aS0[tm][tn][r] + aS1[tm][tn][r] * inv64;
                    float a2 = C * C + S * S;
                    int col = n0 + wn * 64 + tn * 16 + ln;
                    u64 key = ((u64)__float_as_uint(a2) << 32) | (unsigned)(~col);
                    if (key > best) best = key;
                }
                for (int off = 1; off < 16; off <<= 1) {
                    unsigned hi = (unsigned)(best >> 32), lo = (unsigned)best;
                    unsigned ho = __shfl_xor(hi, off);
                    unsigned lo2 = __shfl_xor(lo, off);
                    u64 o = ((u64)ho << 32) | lo2;
                    if (o > best) best = o;
                }
                if (ln == 0) {
                    int grow = rowBase + wm * 32 + tm * 16 + q * 4 + r;
                    if (grow < M_OUT) atomicMax(cells + grow, best);
                }
            }
        }
    }
}

// ================= MID/LOW fallback path =================
__global__ void fill_tables_rm(f16* __restrict__ tbl) {
    long long g = (long long)blockIdx.x * 256 + threadIdx.x;
    if (g >= (long long)(MPAD * 512)) return;
    int m  = (int)(g >> 9);
    int kq = ((int)g & 511) * 8;
    bool valid = (m < M_OUT);
    f16x8 chv, clv, shv, slv;
    for (int j = 0; j < 8; ++j) {
        float c = 0.f, s = 0.f;
        if (valid) {
            int kk = kq + j;
            float ang = CW * (float)(m * kk);
            sincosf(ang, &s, &c);
        }
        f16 h, l;
        split_f16(c, h, l); chv[j] = h; clv[j] = l;
        split_f16(s, h, l); shv[j] = h; slv[j] = l;
    }
    size_t idx = (size_t)m * NDIM + kq;
    *(f16x8*)(tbl + idx)               = chv;
    *(f16x8*)(tbl + A_ELEMS + idx)     = clv;
    *(f16x8*)(tbl + 2 * A_ELEMS + idx) = shv;
    *(f16x8*)(tbl + 3 * A_ELEMS + idx) = slv;
}

#define PK 40   // padded k-stride: all 8 bank groups covered -> 2-way (free)
__global__ __launch_bounds__(256, 2) void dft_gemm_fb(
    const float* __restrict__ x, const float* __restrict__ meanv,
    const f16* __restrict__ tbl, int useTbl,
    u64* __restrict__ cells)
{
    __shared__ alignas(16) f16 Ach[64][PK];
    __shared__ alignas(16) f16 Acl[64][PK];
    __shared__ alignas(16) f16 Ash[64][PK];
    __shared__ alignas(16) f16 Asl[64][PK];
    __shared__ alignas(16) f16 Xh[128][PK];
    __shared__ alignas(16) f16 Xl[128][PK];

    const int t = threadIdx.x;
    const int n0      = blockIdx.x * 128;
    const int rowBase = blockIdx.y * 64;

    const int am  = t >> 2;
    const int akq = (t & 3) * 8;
    const int xn  = t & 127;
    const int xkh = (t >> 7) * 16;

    const int lane = t & 63;
    const int w  = t >> 6;
    const int wm = w >> 1, wn = w & 1;
    const int q  = lane >> 4, ln = lane & 15;

    f32x4 aC0[2][4], aC1[2][4], aS0[2][4], aS1[2][4];
    for (int i = 0; i < 2; ++i)
        for (int j = 0; j < 4; ++j) {
            aC0[i][j] = (f32x4){0.f, 0.f, 0.f, 0.f};
            aC1[i][j] = (f32x4){0.f, 0.f, 0.f, 0.f};
            aS0[i][j] = (f32x4){0.f, 0.f, 0.f, 0.f};
            aS1[i][j] = (f32x4){0.f, 0.f, 0.f, 0.f};
        }

    const int arow = rowBase + am;
    const bool avalid = (arow < M_OUT);

    for (int k0 = 0; k0 < NDIM; k0 += 32) {
        __syncthreads();
        if (useTbl) {
            size_t idx = (size_t)arow * NDIM + k0 + akq;
            *(f16x8*)&Ach[am][akq] = *(const f16x8*)(tbl + idx);
            *(f16x8*)&Acl[am][akq] = *(const f16x8*)(tbl + A_ELEMS + idx);
            *(f16x8*)&Ash[am][akq] = *(const f16x8*)(tbl + 2 * A_ELEMS + idx);
            *(f16x8*)&Asl[am][akq] = *(const f16x8*)(tbl + 3 * A_ELEMS + idx);
        } else {
            f16x8 chv, clv, shv, slv;
            for (int j = 0; j < 8; ++j) {
                float c = 0.f, s = 0.f;
                if (avalid) {
                    int kk = k0 + akq + j;
                    float ang = CW * (float)(arow * kk);
                    sincosf(ang, &s, &c);
                }
                f16 h, l;
                split_f16(c, h, l); chv[j] = h; clv[j] = l;
                split_f16(s, h, l); shv[j] = h; slv[j] = l;
            }
            *(f16x8*)&Ach[am][akq] = chv;
            *(f16x8*)&Acl[am][akq] = clv;
            *(f16x8*)&Ash[am][akq] = shv;
            *(f16x8*)&Asl[am][akq] = slv;
        }
        {
            const float* xp = x + (size_t)(k0 + xkh) * NDIM + n0 + xn;
            f16x8 h0, h1, l0, l1;
            for (int r = 0; r < 16; ++r) {
                float v = xp[(size_t)r * NDIM] - meanv[k0 + xkh + r];
                f16 hi, lo;
                split_f16(v, hi, lo);
                if (r < 8) { h0[r] = hi; l0[r] = lo; }
                else       { h1[r - 8] = hi; l1[r - 8] = lo; }
            }
            *(f16x8*)&Xh[xn][xkh]     = h0;
            *(f16x8*)&Xh[xn][xkh + 8] = h1;
            *(f16x8*)&Xl[xn][xkh]     = l0;
            *(f16x8*)&Xl[xn][xkh + 8] = l1;
        }
        __syncthreads();
        f16x8 fch[2], fcl[2], fsh[2], fsl[2], bh[4], bl[4];
        for (int tm = 0; tm < 2; ++tm) {
            int ml = wm * 32 + tm * 16 + ln;
            fch[tm] = *(const f16x8*)&Ach[ml][q * 8];
            fcl[tm] = *(const f16x8*)&Acl[ml][q * 8];
            fsh[tm] = *(const f16x8*)&Ash[ml][q * 8];
            fsl[tm] = *(const f16x8*)&Asl[ml][q * 8];
        }
        for (int tn = 0; tn < 4; ++tn) {
            int nl = wn * 64 + tn * 16 + ln;
            bh[tn] = *(const f16x8*)&Xh[nl][q * 8];
            bl[tn] = *(const f16x8*)&Xl[nl][q * 8];
        }
        for (int tm = 0; tm < 2; ++tm)
            for (int tn = 0; tn < 4; ++tn) {
                aC0[tm][tn] = __builtin_amdgcn_mfma_f32_16x16x32_f16(fch[tm], bh[tn], aC0[tm][tn], 0, 0, 0);
                aC1[tm][tn] = __builtin_amdgcn_mfma_f32_16x16x32_f16(fch[tm], bl[tn], aC1[tm][tn], 0, 0, 0);
                aC1[tm][tn] = __builtin_amdgcn_mfma_f32_16x16x32_f16(fcl[tm], bh[tn], aC1[tm][tn], 0, 0, 0);
                aS0[tm][tn] = __builtin_amdgcn_mfma_f32_16x16x32_f16(fsh[tm], bh[tn], aS0[tm][tn], 0, 0, 0);
                aS1[tm][tn] = __builtin_amdgcn_mfma_f32_16x16x32_f16(fsh[tm], bl[tn], aS1[tm][tn], 0, 0, 0);
                aS1[tm][tn] = __builtin_amdgcn_mfma_f32_16x16x32_f16(fsl[tm], bh[tn], aS1[tm][tn], 0, 0, 0);
            }
    }

    const float inv64 = 0.015625f;
    for (int tm = 0; tm < 2; ++tm) {
        for (int r = 0; r < 4; ++r) {
            u64 best = 0ull;
            for (int tn = 0; tn < 4; ++tn) {
                float C = aC0[tm][tn][r] + aC1[tm][tn][r] * inv64;
                float S = aS0[tm][tn][r] + aS1[tm][tn][r] * inv64;
                float a2 = C * C + S * S;
                int col = n0 + wn * 64 + tn * 16 + ln;
                u64 key = ((u64)__float_as_uint(a2) << 32) | (unsigned)(~col);
                if (key > best) best = key;
            }
            for (int off = 1; off < 16; off <<= 1) {
                unsigned hi = (unsigned)(best >> 32), lo = (unsigned)best;
                unsigned ho = __shfl_xor(hi, off);
                unsigned lo2 = __shfl_xor(lo, off);
                u64 o = ((u64)ho << 32) | lo2;
                if (o > best) best = o;
            }
            if (ln == 0) {
                int grow = rowBase + wm * 32 + tm * 16 + q * 4 + r;
                if (grow < M_OUT) atomicMax(cells + grow, best);
            }
        }
    }
}

// ---------------- cells -> output ----------------
__global__ void out_kernel(const u64* __restrict__ cells, float* __restrict__ out) {
    int i = blockIdx.x * 256 + threadIdx.x;
    if (i < M_OUT) {
        unsigned col = ~(unsigned)(cells[i] & 0xFFFFFFFFull);
        float freq = (float)col / (4096.0f / 30.0f);
        out[i] = freq * 60.0f;
    }
}

extern "C" void kernel_launch(void* const* d_in, const int* in_sizes, int n_in,
                              void* d_out, int out_size, void* d_ws, size_t ws_size,
                              hipStream_t stream) {
    const float* x = (const float*)d_in[0];
    char* ws = (char*)d_ws;
    float* meanv = (float*)(ws + WS_MEAN);
    u64*   cells = (u64*)(ws + WS_CELLS);
    f16*   atbl  = (f16*)(ws + WS_TBL);
    f16*   xtbl  = (f16*)(ws + WS_XTBL);
    float* out   = (float*)d_out;

    hipLaunchKernelGGL(mean_kernel, dim3(NDIM), dim3(256), 0, stream, x, meanv, cells);

    if (ws_size >= WS_FULL_END) {
        hipLaunchKernelGGL(fill_tables_cm, dim3(512, 25), dim3(256), 0, stream,
                           x, meanv, atbl, xtbl);
        // rows 0..2047 via grid; Nyquist tile (2048..2111) as pass 2 of y==0 blocks
        hipLaunchKernelGGL(dft_gemm_cm, dim3(32, 32), dim3(256), 0, stream, atbl, xtbl, cells);
    } else if (ws_size >= WS_MID_END) {
        hipLaunchKernelGGL(fill_tables_rm, dim3(4224), dim3(256), 0, stream, atbl);
        hipLaunchKernelGGL(dft_gemm_fb, dim3(32, 33), dim3(256), 0, stream,
                           x, meanv, atbl, 1, cells);
    } else {
        hipLaunchKernelGGL(dft_gemm_fb, dim3(32, 33), dim3(256), 0, stream,
                           x, meanv, atbl, 0, cells);
    }
    hipLaunchKernelGGL(out_kernel, dim3((M_OUT + 255) / 256), dim3(256), 0, stream, cells, out);
}

// Round 6
// 455.562 us; speedup vs baseline: 1.1822x; 1.1822x over previous
//
#include <hip/hip_runtime.h>
#include <cmath>

typedef _Float16 f16;
typedef _Float16 f16x8 __attribute__((ext_vector_type(8)));
typedef float f32x4 __attribute__((ext_vector_type(4)));
typedef unsigned long long u64;

#define M_OUT 2049          // N//2 + 1
#define NDIM 4096
#define MPAD 2112           // 2049 padded to 64-multiple (33 tiles)
// reference: -2.0 * 3.14 / N computed in f64, rounded once to f32
#define CW ((float)(-2.0 * 3.14 / 4096.0))

// ws layout:
//   [0, 16384)             row means (4096 f32)
//   [16384, 16384+2049*8)  argmax cells (u64, packed (amp2_bits<<32)|~col)
//   [40960, ...)           tables (layout depends on path)
// FULL path (chunk-major):
//   A tables: Ach,Acl,Ash,Asl each [512][2112][8] f16   (4 x 17.3 MB)
//   X tables: Xh,Xl           each [512][4096][8] f16   (2 x 33.6 MB)
// The A-table region doubles as SCRATCH for the Nyquist partials (512 KB),
// consumed by nyq_reduce BEFORE fill_tables_cm overwrites it (stream order).
// MID path (row-major): Ach,Acl,Ash,Asl each [2112][4096] f16
static const size_t WS_MEAN  = 0;
static const size_t WS_CELLS = 16384;
static const size_t WS_TBL   = 40960;
static const size_t A_ELEMS  = (size_t)MPAD * NDIM;        // 8650752
static const size_t X_ELEMS  = (size_t)NDIM * NDIM;        // 16777216
static const size_t WS_XTBL  = WS_TBL + 4 * A_ELEMS * sizeof(f16);
static const size_t WS_FULL_END = WS_XTBL + 2 * X_ELEMS * sizeof(f16);
static const size_t WS_MID_END  = WS_TBL + 4 * A_ELEMS * sizeof(f16);

#define AS1 __attribute__((address_space(1)))
#define AS3 __attribute__((address_space(3)))
__device__ __forceinline__ void async_copy16(const void* gsrc, void* ldst) {
    __builtin_amdgcn_global_load_lds((const AS1 unsigned int*)gsrc,
                                     (AS3 unsigned int*)ldst, 16, 0, 0);
}

__device__ __forceinline__ void split_f16(float v, f16& hi, f16& lo) {
    hi = (f16)v;
    lo = (f16)((v - (float)hi) * 64.0f);
}

// ---------------- row means (+ argmax-cell init in first 9 blocks) ----------------
__global__ void mean_kernel(const float* __restrict__ x, float* __restrict__ meanv,
                            u64* __restrict__ cells) {
    if (blockIdx.x < 9) {
        int i = blockIdx.x * 256 + threadIdx.x;
        if (i < M_OUT) cells[i] = 0ull;
    }
    const int row = blockIdx.x;
    const float4* xr = (const float4*)(x + (size_t)row * NDIM);
    float s = 0.f;
    for (int i = threadIdx.x; i < NDIM / 4; i += 256) {
        float4 v = xr[i];
        s += (v.x + v.y) + (v.z + v.w);
    }
    for (int off = 32; off; off >>= 1) s += __shfl_down(s, off);
    __shared__ float ps[4];
    if ((threadIdx.x & 63) == 0) ps[threadIdx.x >> 6] = s;
    __syncthreads();
    if (threadIdx.x == 0) {
        float t = (ps[0] + ps[1]) + (ps[2] + ps[3]);
        meanv[row] = t * (1.0f / 4096.0f);
    }
}

// ---------------- Nyquist row (m = 2048), two-stage deterministic f32 ----------
// Stage 1: grid (32 colgroups, 16 kslabs), 512 blocks (2/CU). Block covers
// 128 cols x 256 k. Per-block sincos table in LDS (256 sincosf total).
// Thread: 128 coalesced strided loads, f32 fma chain. 2 k-partitions reduced
// via LDS in fixed (lower+upper) order. Partials -> scratch (A-table region).
__global__ __launch_bounds__(256) void nyq_partial(
    const float* __restrict__ x, const float* __restrict__ meanv,
    float* __restrict__ part)     // [2][16][4096] f32 = 512 KB
{
    __shared__ float lc[256], ls[256];
    __shared__ float sC[128], sS[128];
    const int t = threadIdx.x;
    const int ks = blockIdx.y;                 // 0..15
    const int kbase = ks * 256;
    sincosf(CW * (float)(2048 * (kbase + t)), &ls[t], &lc[t]);
    __syncthreads();
    const int col = blockIdx.x * 128 + (t & 127);
    const int kp  = t >> 7;                    // 0/1
    float C = 0.f, S = 0.f;
    const float* xp = x + (size_t)(kbase + kp * 128) * NDIM + col;
    const float* mp = meanv + kbase + kp * 128;
    for (int i = 0; i < 128; ++i) {
        float v = xp[(size_t)i * NDIM] - mp[i];
        C = fmaf(lc[kp * 128 + i], v, C);
        S = fmaf(ls[kp * 128 + i], v, S);
    }
    if (kp) { sC[t - 128] = C; sS[t - 128] = S; }
    __syncthreads();
    if (!kp) {
        part[(size_t)ks * NDIM + col]            = C + sC[t];
        part[(size_t)(16 + ks) * NDIM + col]     = S + sS[t];
    }
}

// Stage 2: 4096 threads, each sums its column's 16 slab partials in fixed
// order (deterministic), computes amp^2, wave-max, atomicMax cells[2048].
__global__ __launch_bounds__(256) void nyq_reduce(
    const float* __restrict__ part, u64* __restrict__ cells)
{
    const int n = blockIdx.x * 256 + threadIdx.x;   // 16 blocks
    float C = 0.f, S = 0.f;
    for (int ks = 0; ks < 16; ++ks) {
        C += part[(size_t)ks * NDIM + n];
        S += part[(size_t)(16 + ks) * NDIM + n];
    }
    float a2 = C * C + S * S;
    u64 key = ((u64)__float_as_uint(a2) << 32) | (unsigned)(~n);
    for (int off = 1; off < 64; off <<= 1) {
        unsigned hi = (unsigned)(key >> 32), lo = (unsigned)key;
        unsigned ho = __shfl_xor(hi, off), lo2 = __shfl_xor(lo, off);
        u64 o = ((u64)ho << 32) | lo2;
        if (o > key) key = o;
    }
    if ((threadIdx.x & 63) == 0) atomicMax(cells + 2048, key);
}

// ================= FULL path: chunk-major tables (A + X merged, one launch) ========
// grid (512, 25): y in [0,9) -> A-table rows tile, y in [9,25) -> X-table col tile.
__global__ void fill_tables_cm(const float* __restrict__ x, const float* __restrict__ meanv,
                               f16* __restrict__ atbl, f16* __restrict__ xtbl) {
    const int c = blockIdx.x;                      // k-chunk 0..511
    if (blockIdx.y < 9) {
        const int m = blockIdx.y * 256 + threadIdx.x;  // 0..2303
        if (m >= MPAD) return;
        const bool valid = (m < M_OUT);
        f16x8 chv, clv, shv, slv;
        for (int j = 0; j < 8; ++j) {
            float cc = 0.f, ss = 0.f;
            if (valid) {
                int kk = c * 8 + j;
                float ang = CW * (float)(m * kk);      // m*kk < 2^24 -> exact
                sincosf(ang, &ss, &cc);
            }
            f16 h, l;
            split_f16(cc, h, l); chv[j] = h; clv[j] = l;
            split_f16(ss, h, l); shv[j] = h; slv[j] = l;
        }
        size_t idx = ((size_t)c * MPAD + m) * 8;
        *(f16x8*)(atbl + idx)                 = chv;
        *(f16x8*)(atbl + A_ELEMS + idx)       = clv;
        *(f16x8*)(atbl + 2 * A_ELEMS + idx)   = shv;
        *(f16x8*)(atbl + 3 * A_ELEMS + idx)   = slv;
    } else {
        const int n = (blockIdx.y - 9) * 256 + threadIdx.x;  // 0..4095
        f16x8 hv, lv;
        for (int j = 0; j < 8; ++j) {
            int k = c * 8 + j;
            float v = x[(size_t)k * NDIM + n] - meanv[k];
            f16 h, l;
            split_f16(v, h, l);
            hv[j] = h; lv[j] = l;
        }
        size_t idx = ((size_t)c * NDIM + n) * 8;
        *(f16x8*)(xtbl + idx)           = hv;
        *(f16x8*)(xtbl + X_ELEMS + idx) = lv;
    }
}

// Fused split-f16 DFT GEMM + argmax.
// A fragments: direct global->VGPR (contiguous 16B, chunk-major), double-buffered regs.
// X: TRIPLE-buffered LDS via global_load_lds.
// Pipeline: per K=32 phase, issue next phase's 8 A-loads + 4 X-DMAs at the TOP,
// raw s_barrier with COUNTED s_waitcnt vmcnt(12) (prev phase's batch drained;
// this phase's 12 stay in flight across the barrier). sched_barrier(0) after each
// s_barrier pins the ds_reads after the rendezvous. 3 X buffers make the restage
// WAR-safe. s_setprio(1) around the 48-MFMA cluster.
// Grid: 32 x 32 = 1024 blocks = EXACTLY 2 occupancy rounds at 2 blocks/CU
// (rows 0..2047; Nyquist row handled by nyq_partial/nyq_reduce).
// Tile: BM=64 x BN=128 x BK=32. 256 threads = 4 waves (2x2 of 32x64).
__global__ __launch_bounds__(256, 2) void dft_gemm_cm(
    const f16* __restrict__ atbl, const f16* __restrict__ xtbl,
    u64* __restrict__ cells)
{
    __shared__ alignas(16) f16 sX[3][2][4][128][8];   // [buf][tbl][plane][n][8] = 48 KB

    const int t = threadIdx.x;
    const int n0      = blockIdx.x * 128;
    const int rowBase = blockIdx.y * 64;

    const int lane = t & 63;
    const int w  = t >> 6;
    const int wm = w >> 1, wn = w & 1;
    const int q  = lane >> 4, ln = lane & 15;

    f32x4 aC0[2][4], aC1[2][4], aS0[2][4], aS1[2][4];
#pragma unroll
    for (int i = 0; i < 2; ++i)
#pragma unroll
        for (int j = 0; j < 4; ++j) {
            aC0[i][j] = (f32x4){0.f, 0.f, 0.f, 0.f};
            aC1[i][j] = (f32x4){0.f, 0.f, 0.f, 0.f};
            aS0[i][j] = (f32x4){0.f, 0.f, 0.f, 0.f};
            aS1[i][j] = (f32x4){0.f, 0.f, 0.f, 0.f};
        }

    // A-fragment global base: row = rowBase + wm*32 + tm*16 + ln, chunk = kc + q
    const f16* aBase = atbl + ((size_t)q * MPAD + (rowBase + wm * 32 + ln)) * 8;

    // X staging: 4 async ops per wave cover [2 tables][4 planes][2 halves]
    const int xq0 = w >> 1, xh = w & 1;
    const int xq1 = xq0 + 2;
    const f16* xG0 = xtbl + ((size_t)xq0 * NDIM + n0 + xh * 64 + lane) * 8;
    const f16* xG1 = xtbl + ((size_t)xq1 * NDIM + n0 + xh * 64 + lane) * 8;
    const f16* xG2 = xG0 + X_ELEMS;
    const f16* xG3 = xG1 + X_ELEMS;

    auto loadA = [&](f16x8 (&dst)[2][4], int kc) {
#pragma unroll
        for (int tm = 0; tm < 2; ++tm)
#pragma unroll
            for (int tb = 0; tb < 4; ++tb)
                dst[tm][tb] = *(const f16x8*)(aBase + (size_t)tb * A_ELEMS
                              + ((size_t)kc * MPAD + tm * 16) * 8);
    };

    auto stageX = [&](int buf, int kc) {
        const size_t kadv = (size_t)kc * NDIM * 8;
        async_copy16(xG0 + kadv, &sX[buf][0][xq0][xh * 64][0]);
        async_copy16(xG1 + kadv, &sX[buf][0][xq1][xh * 64][0]);
        async_copy16(xG2 + kadv, &sX[buf][1][xq0][xh * 64][0]);
        async_copy16(xG3 + kadv, &sX[buf][1][xq1][xh * 64][0]);
    };

    auto compute = [&](f16x8 (&A)[2][4], int buf) {
        f16x8 bh[4], bl[4];
#pragma unroll
        for (int tn = 0; tn < 4; ++tn) {
            int nl = wn * 64 + tn * 16 + ln;
            bh[tn] = *(const f16x8*)&sX[buf][0][q][nl][0];
            bl[tn] = *(const f16x8*)&sX[buf][1][q][nl][0];
        }
        __builtin_amdgcn_s_setprio(1);
#pragma unroll
        for (int tm = 0; tm < 2; ++tm)
#pragma unroll
            for (int tn = 0; tn < 4; ++tn) {
                aC0[tm][tn] = __builtin_amdgcn_mfma_f32_16x16x32_f16(A[tm][0], bh[tn], aC0[tm][tn], 0, 0, 0);
                aC1[tm][tn] = __builtin_amdgcn_mfma_f32_16x16x32_f16(A[tm][0], bl[tn], aC1[tm][tn], 0, 0, 0);
                aC1[tm][tn] = __builtin_amdgcn_mfma_f32_16x16x32_f16(A[tm][1], bh[tn], aC1[tm][tn], 0, 0, 0);
                aS0[tm][tn] = __builtin_amdgcn_mfma_f32_16x16x32_f16(A[tm][2], bh[tn], aS0[tm][tn], 0, 0, 0);
                aS1[tm][tn] = __builtin_amdgcn_mfma_f32_16x16x32_f16(A[tm][2], bl[tn], aS1[tm][tn], 0, 0, 0);
                aS1[tm][tn] = __builtin_amdgcn_mfma_f32_16x16x32_f16(A[tm][3], bh[tn], aS1[tm][tn], 0, 0, 0);
            }
        __builtin_amdgcn_s_setprio(0);
    };

    f16x8 Aa[2][4], Ab[2][4];
    int cur = 0, nxt = 1;
    auto bump = [&]() { cur = nxt; nxt = (nxt == 2) ? 0 : nxt + 1; };

    // prologue: phase 0's batch in flight
    stageX(0, 0);
    loadA(Aa, 0);

    int kc = 0;   // chunk index (8 f16 per chunk); K=32 per phase -> step 4; 128 phases
    for (int it = 0; it < 63; ++it) {
        // even phase: compute Aa/buf cur, issue batch for next phase
        loadA(Ab, kc + 4);
        stageX(nxt, kc + 4);
        asm volatile("s_waitcnt vmcnt(12)" ::: "memory");   // previous batch landed; 12 new fly on
        __builtin_amdgcn_s_barrier();
        __builtin_amdgcn_sched_barrier(0);
        compute(Aa, cur);
        bump();
        kc += 4;
        // odd phase
        loadA(Aa, kc + 4);
        stageX(nxt, kc + 4);
        asm volatile("s_waitcnt vmcnt(12)" ::: "memory");
        __builtin_amdgcn_s_barrier();
        __builtin_amdgcn_sched_barrier(0);
        compute(Ab, cur);
        bump();
        kc += 4;
    }
    // phase 126: issue final batch (chunks 508..511)
    loadA(Ab, kc + 4);
    stageX(nxt, kc + 4);
    asm volatile("s_waitcnt vmcnt(12)" ::: "memory");
    __builtin_amdgcn_s_barrier();
    __builtin_amdgcn_sched_barrier(0);
    compute(Aa, cur);
    bump();
    // phase 127: last — full drain
    asm volatile("s_waitcnt vmcnt(0)" ::: "memory");
    __builtin_amdgcn_s_barrier();
    __builtin_amdgcn_sched_barrier(0);
    compute(Ab, cur);

    // ---- epilogue: amp^2, per-row argmax, atomicMax into cells ----
    const float inv64 = 0.015625f;
#pragma unroll
    for (int tm = 0; tm < 2; ++tm) {
#pragma unroll
        for (int r = 0; r < 4; ++r) {
            u64 best = 0ull;
#pragma unroll
            for (int tn = 0; tn < 4; ++tn) {
                float C = aC0[tm][tn][r] + aC1[tm][tn][r] * inv64;
                float S = aS0[tm][tn][r] + aS1[tm][tn][r] * inv64;
                float a2 = C * C + S * S;
                int col = n0 + wn * 64 + tn * 16 + ln;
                u64 key = ((u64)__float_as_uint(a2) << 32) | (unsigned)(~col);
                if (key > best) best = key;
            }
            for (int off = 1; off < 16; off <<= 1) {
                unsigned hi = (unsigned)(best >> 32), lo = (unsigned)best;
                unsigned ho = __shfl_xor(hi, off);
                unsigned lo2 = __shfl_xor(lo, off);
                u64 o = ((u64)ho << 32) | lo2;
                if (o > best) best = o;
            }
            if (ln == 0) {
                int grow = rowBase + wm * 32 + tm * 16 + q * 4 + r;
                if (grow < M_OUT) atomicMax(cells + grow, best);
            }
        }
    }
}

// ================= MID/LOW fallback path =================
__global__ void fill_tables_rm(f16* __restrict__ tbl) {
    long long g = (long long)blockIdx.x * 256 + threadIdx.x;
    if (g >= (long long)(MPAD * 512)) return;
    int m  = (int)(g >> 9);
    int kq = ((int)g & 511) * 8;
    bool valid = (m < M_OUT);
    f16x8 chv, clv, shv, slv;
    for (int j = 0; j < 8; ++j) {
        float c = 0.f, s = 0.f;
        if (valid) {
            int kk = kq + j;
            float ang = CW * (float)(m * kk);
            sincosf(ang, &s, &c);
        }
        f16 h, l;
        split_f16(c, h, l); chv[j] = h; clv[j] = l;
        split_f16(s, h, l); shv[j] = h; slv[j] = l;
    }
    size_t idx = (size_t)m * NDIM + kq;
    *(f16x8*)(tbl + idx)               = chv;
    *(f16x8*)(tbl + A_ELEMS + idx)     = clv;
    *(f16x8*)(tbl + 2 * A_ELEMS + idx) = shv;
    *(f16x8*)(tbl + 3 * A_ELEMS + idx) = slv;
}

#define PK 40   // padded k-stride: all 8 bank groups covered -> 2-way (free)
__global__ __launch_bounds__(256, 2) void dft_gemm_fb(
    const float* __restrict__ x, const float* __restrict__ meanv,
    const f16* __restrict__ tbl, int useTbl,
    u64* __restrict__ cells)
{
    __shared__ alignas(16) f16 Ach[64][PK];
    __shared__ alignas(16) f16 Acl[64][PK];
    __shared__ alignas(16) f16 Ash[64][PK];
    __shared__ alignas(16) f16 Asl[64][PK];
    __shared__ alignas(16) f16 Xh[128][PK];
    __shared__ alignas(16) f16 Xl[128][PK];

    const int t = threadIdx.x;
    const int n0      = blockIdx.x * 128;
    const int rowBase = blockIdx.y * 64;

    const int am  = t >> 2;
    const int akq = (t & 3) * 8;
    const int xn  = t & 127;
    const int xkh = (t >> 7) * 16;

    const int lane = t & 63;
    const int w  = t >> 6;
    const int wm = w >> 1, wn = w & 1;
    const int q  = lane >> 4, ln = lane & 15;

    f32x4 aC0[2][4], aC1[2][4], aS0[2][4], aS1[2][4];
    for (int i = 0; i < 2; ++i)
        for (int j = 0; j < 4; ++j) {
            aC0[i][j] = (f32x4){0.f, 0.f, 0.f, 0.f};
            aC1[i][j] = (f32x4){0.f, 0.f, 0.f, 0.f};
            aS0[i][j] = (f32x4){0.f, 0.f, 0.f, 0.f};
            aS1[i][j] = (f32x4){0.f, 0.f, 0.f, 0.f};
        }

    const int arow = rowBase + am;
    const bool avalid = (arow < M_OUT);

    for (int k0 = 0; k0 < NDIM; k0 += 32) {
        __syncthreads();
        if (useTbl) {
            size_t idx = (size_t)arow * NDIM + k0 + akq;
            *(f16x8*)&Ach[am][akq] = *(const f16x8*)(tbl + idx);
            *(f16x8*)&Acl[am][akq] = *(const f16x8*)(tbl + A_ELEMS + idx);
            *(f16x8*)&Ash[am][akq] = *(const f16x8*)(tbl + 2 * A_ELEMS + idx);
            *(f16x8*)&Asl[am][akq] = *(const f16x8*)(tbl + 3 * A_ELEMS + idx);
        } else {
            f16x8 chv, clv, shv, slv;
            for (int j = 0; j < 8; ++j) {
                float c = 0.f, s = 0.f;
                if (avalid) {
                    int kk = k0 + akq + j;
                    float ang = CW * (float)(arow * kk);
                    sincosf(ang, &s, &c);
                }
                f16 h, l;
                split_f16(c, h, l); chv[j] = h; clv[j] = l;
                split_f16(s, h, l); shv[j] = h; slv[j] = l;
            }
            *(f16x8*)&Ach[am][akq] = chv;
            *(f16x8*)&Acl[am][akq] = clv;
            *(f16x8*)&Ash[am][akq] = shv;
            *(f16x8*)&Asl[am][akq] = slv;
        }
        {
            const float* xp = x + (size_t)(k0 + xkh) * NDIM + n0 + xn;
            f16x8 h0, h1, l0, l1;
            for (int r = 0; r < 16; ++r) {
                float v = xp[(size_t)r * NDIM] - meanv[k0 + xkh + r];
                f16 hi, lo;
                split_f16(v, hi, lo);
                if (r < 8) { h0[r] = hi; l0[r] = lo; }
                else       { h1[r - 8] = hi; l1[r - 8] = lo; }
            }
            *(f16x8*)&Xh[xn][xkh]     = h0;
            *(f16x8*)&Xh[xn][xkh + 8] = h1;
            *(f16x8*)&Xl[xn][xkh]     = l0;
            *(f16x8*)&Xl[xn][xkh + 8] = l1;
        }
        __syncthreads();
        f16x8 fch[2], fcl[2], fsh[2], fsl[2], bh[4], bl[4];
        for (int tm = 0; tm < 2; ++tm) {
            int ml = wm * 32 + tm * 16 + ln;
            fch[tm] = *(const f16x8*)&Ach[ml][q * 8];
            fcl[tm] = *(const f16x8*)&Acl[ml][q * 8];
            fsh[tm] = *(const f16x8*)&Ash[ml][q * 8];
            fsl[tm] = *(const f16x8*)&Asl[ml][q * 8];
        }
        for (int tn = 0; tn < 4; ++tn) {
            int nl = wn * 64 + tn * 16 + ln;
            bh[tn] = *(const f16x8*)&Xh[nl][q * 8];
            bl[tn] = *(const f16x8*)&Xl[nl][q * 8];
        }
        for (int tm = 0; tm < 2; ++tm)
            for (int tn = 0; tn < 4; ++tn) {
                aC0[tm][tn] = __builtin_amdgcn_mfma_f32_16x16x32_f16(fch[tm], bh[tn], aC0[tm][tn], 0, 0, 0);
                aC1[tm][tn] = __builtin_amdgcn_mfma_f32_16x16x32_f16(fch[tm], bl[tn], aC1[tm][tn], 0, 0, 0);
                aC1[tm][tn] = __builtin_amdgcn_mfma_f32_16x16x32_f16(fcl[tm], bh[tn], aC1[tm][tn], 0, 0, 0);
                aS0[tm][tn] = __builtin_amdgcn_mfma_f32_16x16x32_f16(fsh[tm], bh[tn], aS0[tm][tn], 0, 0, 0);
                aS1[tm][tn] = __builtin_amdgcn_mfma_f32_16x16x32_f16(fsh[tm], bl[tn], aS1[tm][tn], 0, 0, 0);
                aS1[tm][tn] = __builtin_amdgcn_mfma_f32_16x16x32_f16(fsl[tm], bh[tn], aS1[tm][tn], 0, 0, 0);
            }
    }

    const float inv64 = 0.015625f;
    for (int tm = 0; tm < 2; ++tm) {
        for (int r = 0; r < 4; ++r) {
            u64 best = 0ull;
            for (int tn = 0; tn < 4; ++tn) {
                float C = aC0[tm][tn][r] + aC1[tm][tn][r] * inv64;
                float S = aS0[tm][tn][r] + aS1[tm][tn][r] * inv64;
                float a2 = C * C + S * S;
                int col = n0 + wn * 64 + tn * 16 + ln;
                u64 key = ((u64)__float_as_uint(a2) << 32) | (unsigned)(~col);
                if (key > best) best = key;
            }
            for (int off = 1; off < 16; off <<= 1) {
                unsigned hi = (unsigned)(best >> 32), lo = (unsigned)best;
                unsigned ho = __shfl_xor(hi, off);
                unsigned lo2 = __shfl_xor(lo, off);
                u64 o = ((u64)ho << 32) | lo2;
                if (o > best) best = o;
            }
            if (ln == 0) {
                int grow = rowBase + wm * 32 + tm * 16 + q * 4 + r;
                if (grow < M_OUT) atomicMax(cells + grow, best);
            }
        }
    }
}

// ---------------- cells -> output ----------------
__global__ void out_kernel(const u64* __restrict__ cells, float* __restrict__ out) {
    int i = blockIdx.x * 256 + threadIdx.x;
    if (i < M_OUT) {
        unsigned col = ~(unsigned)(cells[i] & 0xFFFFFFFFull);
        float freq = (float)col / (4096.0f / 30.0f);
        out[i] = freq * 60.0f;
    }
}

extern "C" void kernel_launch(void* const* d_in, const int* in_sizes, int n_in,
                              void* d_out, int out_size, void* d_ws, size_t ws_size,
                              hipStream_t stream) {
    const float* x = (const float*)d_in[0];
    char* ws = (char*)d_ws;
    float* meanv = (float*)(ws + WS_MEAN);
    u64*   cells = (u64*)(ws + WS_CELLS);
    f16*   atbl  = (f16*)(ws + WS_TBL);
    f16*   xtbl  = (f16*)(ws + WS_XTBL);
    float* nyqp  = (float*)(ws + WS_TBL);   // scratch, consumed before table fill
    float* out   = (float*)d_out;

    hipLaunchKernelGGL(mean_kernel, dim3(NDIM), dim3(256), 0, stream, x, meanv, cells);

    if (ws_size >= WS_FULL_END) {
        // Nyquist row first (uses A-table region as scratch, then freed)
        hipLaunchKernelGGL(nyq_partial, dim3(32, 16), dim3(256), 0, stream, x, meanv, nyqp);
        hipLaunchKernelGGL(nyq_reduce, dim3(16), dim3(256), 0, stream, nyqp, cells);
        hipLaunchKernelGGL(fill_tables_cm, dim3(512, 25), dim3(256), 0, stream,
                           x, meanv, atbl, xtbl);
        // rows 0..2047: 32x32 = 1024 blocks = exactly 2 rounds at 2 blocks/CU
        hipLaunchKernelGGL(dft_gemm_cm, dim3(32, 32), dim3(256), 0, stream, atbl, xtbl, cells);
    } else if (ws_size >= WS_MID_END) {
        hipLaunchKernelGGL(fill_tables_rm, dim3(4224), dim3(256), 0, stream, atbl);
        hipLaunchKernelGGL(dft_gemm_fb, dim3(32, 33), dim3(256), 0, stream,
                           x, meanv, atbl, 1, cells);
    } else {
        hipLaunchKernelGGL(dft_gemm_fb, dim3(32, 33), dim3(256), 0, stream,
                           x, meanv, atbl, 0, cells);
    }
    hipLaunchKernelGGL(out_kernel, dim3((M_OUT + 255) / 256), dim3(256), 0, stream, cells, out);
}